// Round 6
// baseline (218.687 us; speedup 1.0000x reference)
//
#include <hip/hip_runtime.h>

typedef unsigned short u16;
typedef unsigned int u32;
typedef float v4f __attribute__((ext_vector_type(4)));
typedef __bf16 bf16x8 __attribute__((ext_vector_type(8)));

#define BATCH 8
#define CDIM 768
#define NHEAD 12
#define DH 64
#define NSEQ 1024
#define SCL 0.18033688011112042f

__device__ __forceinline__ u16 f2bf(float f) {
  u32 u = __builtin_bit_cast(u32, f);
  u += 0x7fffu + ((u >> 16) & 1u);   // RNE
  return (u16)(u >> 16);
}

__device__ __forceinline__ u16 b16(float f) {
  return (u16)((__builtin_bit_cast(u32, f) + 0x8000u) >> 16);
}

__device__ __forceinline__ u32 pkbf(float hi, float lo) {
  u32 a = __builtin_bit_cast(u32, hi) + 0x8000u;
  u32 b = __builtin_bit_cast(u32, lo) + 0x8000u;
  return __builtin_amdgcn_perm(a, b, 0x07060302u);  // {a[31:16], b[31:16]}
}

__device__ __forceinline__ v4f mfma16(bf16x8 a, bf16x8 b, v4f c) {
  return __builtin_amdgcn_mfma_f32_16x16x32_bf16(a, b, c, 0, 0, 0);
}

__device__ __forceinline__ void gload16(const u16* g, u16* l) {
  __builtin_amdgcn_global_load_lds(
      (const __attribute__((address_space(1))) void*)g,
      (__attribute__((address_space(3))) void*)l, 16, 0, 0);
}

// ------------- kernel: fused prep --------------------------------------
__global__ __launch_bounds__(256) void k_prep(const float* __restrict__ x,
                                              const float* __restrict__ wq,
                                              const float* __restrict__ wp,
                                              u16* __restrict__ xT,
                                              u16* __restrict__ wqb,
                                              u16* __restrict__ wpb) {
  __shared__ u16 Ts[64][72];
  int bid = blockIdx.x;
  int t = threadIdx.x;
  if (bid < 2304) {
    bool isQ = bid < 1728;
    const float* s = isQ ? wq : wp;
    u16* d = isQ ? wqb : wpb;
    int i = (isQ ? bid : bid - 1728) * 256 + t;
    float4 v = ((const float4*)s)[i];
    u32 lo = (u32)f2bf(v.x) | ((u32)f2bf(v.y) << 16);
    u32 hi = (u32)f2bf(v.z) | ((u32)f2bf(v.w) << 16);
    ((uint2*)d)[i] = uint2{lo, hi};
    return;
  }
  int id = bid - 2304;
  int p0 = (id & 15) * 64; id >>= 4;
  int c0 = (id % 12) * 64; int b = id / 12;
  int cr = t >> 4;
  int p4 = (t & 15) * 4;
  const float* src = x + ((size_t)b * CDIM + c0) * NSEQ + p0;
#pragma unroll
  for (int i = 0; i < 4; ++i) {
    int c = cr + i * 16;
    float4 v = *(const float4*)&src[(size_t)c * NSEQ + p4];
    Ts[p4 + 0][c] = f2bf(v.x);
    Ts[p4 + 1][c] = f2bf(v.y);
    Ts[p4 + 2][c] = f2bf(v.z);
    Ts[p4 + 3][c] = f2bf(v.w);
  }
  __syncthreads();
  int p = t >> 2;
  int cq = t & 3;
  u16* dst = xT + ((size_t)b * NSEQ + p0 + p) * CDIM + c0;
#pragma unroll
  for (int j = 0; j < 2; ++j) {
    int ch = cq + j * 4;
    *(int4*)&dst[ch * 8] = *(const int4*)&Ts[p][ch * 8];
  }
}

// ------------- 256x128 double-buffered pipelined GEMM core --------------
// R4-proven 2-phase structure (4 barriers/K-tile, same swizzle/addressing)
// but DBUF 48 KB -> 3 blocks/CU (3 independent barrier groups per CU so
// one block's stalls overlap other blocks' MFMA/LDS phases; qkv grid 576
// fits 768 slots = single round, no tail).
// Buffer = 24 KB: A chunks (64 rows x 32 k each) at u16 offsets
// {A0:0, A1:2048, A2:4096, A3:6144}, B chunks {B0:8192, B1:10240}.
// Phase A reads {A0,A2,B0,B1} of tile kt, phase B reads {A1,A3}.
// Stage sets for tile kt+1: S_A={A0,A2,B0,B1} issued in phase A,
// S_B={A1,A3} in phase B. Counted waits (per-wave ledger, steady state):
//   phase A: after S_A issue, in-flight = S_B(kt-1)[2]+S_A(kt)[4]=6
//            -> vmcnt(4) drains S_B(kt-1) (= tile kt's {A1,A3})
//   phase B: after S_B issue, in-flight = S_A(kt)[4]+S_B(kt)[2]=6
//            -> vmcnt(2) drains S_A(kt) (= tile kt+1's phase-A set)
// Cross-wave visibility: each wave drains its OWN DMAs then hits the
// barrier -> after barrier all waves' chunks resident. Never drains to 0
// mid-loop; last iter uses vmcnt(0) at phase A only.
#define NKT 24     // CDIM/32

__device__ __forceinline__ void gemm_core(const u16* __restrict__ Ag,
                                          const u16* __restrict__ Bg,
                                          u16* sm, v4f (&acc)[8][4]) {
  int t = threadIdx.x, lane = t & 63, wid = t >> 6;
  int ln = lane & 15, quad = lane >> 4;
  int wm = wid >> 1, wn = wid & 1;

  // staging: per gload16 each wave covers 16 rows (4 lanes/row, 4 chunks).
  // stored chunk slot (l&3) sources global chunk (l&3)^((l>>3)&3)
  // [= (l&3)^((row>>1)&3) since row = slab + wid*16 + (l>>2)].
  int srow = wid * 16 + (lane >> 2);
  int scg = ((lane & 3) ^ ((lane >> 3) & 3)) * 8;
  const u16* As0 = Ag + (size_t)srow * CDIM + scg;
  const u16* Bs0 = Bg + (size_t)srow * CDIM + scg;
  int ldw = wid * 512;   // u16, wave offset inside a 2048-u16 (64-row) chunk

  // fragment reads: global chunk quad at row r lives in slot quad^((r>>1)&3)
  int cA = (quad ^ ((ln >> 1) & 3)) * 8;
  int rA = (wm * 128 + ln) * 32;            // A region base (u16)
  int rB = 8192 + (wn * 64 + ln) * 32;      // B region at 8192

  // ---- prologue: tile 0 -> buf 0; S_A first (order matters for vmcnt) ----
  {
    u16* s0 = sm;
    gload16(As0, s0 + ldw);                                   // A0
    gload16(As0 + (size_t)128 * CDIM, s0 + 4096 + ldw);       // A2
    gload16(Bs0, s0 + 8192 + ldw);                            // B0
    gload16(Bs0 + (size_t)64 * CDIM, s0 + 10240 + ldw);       // B1
  }
  asm volatile("" ::: "memory");   // keep S_A older than S_B (vmcnt counts)
  {
    u16* s0 = sm;
    gload16(As0 + (size_t)64 * CDIM, s0 + 2048 + ldw);        // A1
    gload16(As0 + (size_t)192 * CDIM, s0 + 6144 + ldw);       // A3
  }
  asm volatile("s_waitcnt vmcnt(2)" ::: "memory");   // {A0,A2,B0,B1} resident
  asm volatile("s_barrier" ::: "memory");

  for (int kt = 0; kt < NKT; ++kt) {
    const u16* sb = sm + (kt & 1) * 12288;       // compute buffer
    u16* nb = sm + ((kt + 1) & 1) * 12288;       // stage target (kt+1)
    int ko = (kt + 1) * 32;

    // ---- phase A: read {A0,A2,B0,B1}; stage S_A(kt+1); MFMA m0-3 ----
    bf16x8 af[4], bfr[4];
#pragma unroll
    for (int m = 0; m < 4; ++m)
      af[m] = *(const bf16x8*)&sb[rA + m * 512 + cA];
#pragma unroll
    for (int n = 0; n < 4; ++n)
      bfr[n] = *(const bf16x8*)&sb[rB + n * 512 + cA];
    if (kt < NKT - 1) {
      gload16(As0 + ko, nb + ldw);                                // A0
      gload16(As0 + (size_t)128 * CDIM + ko, nb + 4096 + ldw);    // A2
      gload16(Bs0 + ko, nb + 8192 + ldw);                         // B0
      gload16(Bs0 + (size_t)64 * CDIM + ko, nb + 10240 + ldw);    // B1
      asm volatile("s_waitcnt vmcnt(4)" ::: "memory");  // drain kt's {A1,A3}
    } else {
      asm volatile("s_waitcnt vmcnt(0)" ::: "memory");  // tail drain
    }
    asm volatile("s_barrier" ::: "memory");
    asm volatile("s_waitcnt lgkmcnt(0)" ::: "memory");
    __builtin_amdgcn_sched_barrier(0);
    __builtin_amdgcn_s_setprio(1);
#pragma unroll
    for (int m = 0; m < 4; ++m)
#pragma unroll
      for (int n = 0; n < 4; ++n)
        acc[m][n] = mfma16(af[m], bfr[n], acc[m][n]);
    __builtin_amdgcn_s_setprio(0);
    asm volatile("s_barrier" ::: "memory");

    // ---- phase B: read {A1,A3}; stage S_B(kt+1); MFMA m4-7 ----
#pragma unroll
    for (int m = 0; m < 4; ++m)
      af[m] = *(const bf16x8*)&sb[rA + (m + 4) * 512 + cA];
    if (kt < NKT - 1) {
      gload16(As0 + (size_t)64 * CDIM + ko, nb + 2048 + ldw);     // A1
      gload16(As0 + (size_t)192 * CDIM + ko, nb + 6144 + ldw);    // A3
      asm volatile("s_waitcnt vmcnt(2)" ::: "memory");  // drain S_A(kt+1)
    }
    asm volatile("s_barrier" ::: "memory");
    asm volatile("s_waitcnt lgkmcnt(0)" ::: "memory");
    __builtin_amdgcn_sched_barrier(0);
    __builtin_amdgcn_s_setprio(1);
#pragma unroll
    for (int m = 0; m < 4; ++m)
#pragma unroll
      for (int n = 0; n < 4; ++n)
        acc[m + 4][n] = mfma16(af[m], bfr[n], acc[m + 4][n]);
    __builtin_amdgcn_s_setprio(0);
    asm volatile("s_barrier" ::: "memory");
  }
}

// ------------- kernel: QKV GEMM  D[o][p] = sum_c W[o][c] * xT[p][c] -----
// 576 blocks (9 oT x 64 p-panels) at 3 blocks/CU -> fully resident, no
// tail. XCD swizzle: XCD x gets pIdx in [8x,8x+8) = exactly batch x
// (1.5 MB xT L2-resident) x all 9 o-tiles.
__global__ __launch_bounds__(256, 3) void k_gemm_qkv(const u16* __restrict__ Wb,
                                                     const u16* __restrict__ xT,
                                                     u16* __restrict__ qkT,
                                                     u16* __restrict__ vbuf) {
  __shared__ u16 sm[2 * 12288];   // 48 KB
  int bid = blockIdx.x;
  int swz = (bid & 7) * 72 + (bid >> 3);   // bijective: 576 % 8 == 0
  int oIdx = swz % 9, pIdx = swz / 9;
  int oT = oIdx * 256;
  int pG = pIdx * 128;                     // global p row (b*1024 + p)

  v4f acc[8][4] = {};
  gemm_core(Wb + (size_t)oT * CDIM, xT + (size_t)pG * CDIM, sm, acc);

  int t = threadIdx.x, lane = t & 63, wid = t >> 6;
  int ln = lane & 15, quad = lane >> 4;
  int wm = wid >> 1, wn = wid & 1;
  bool isV = oT >= 2 * CDIM;               // oIdx 6,7,8
#pragma unroll
  for (int m = 0; m < 8; ++m) {
#pragma unroll
    for (int n = 0; n < 4; ++n) {
      int ro = oT + wm * 128 + m * 16 + quad * 4;   // 4 consecutive o rows
      int cp = pG + wn * 64 + n * 16 + ln;
      int b = cp >> 10, p = cp & 1023;
      if (!isV) {
        u32 lo = (u32)f2bf(acc[m][n][0]) | ((u32)f2bf(acc[m][n][1]) << 16);
        u32 hi = (u32)f2bf(acc[m][n][2]) | ((u32)f2bf(acc[m][n][3]) << 16);
        *(uint2*)&qkT[((size_t)b * NSEQ + p) * 1536 + ro] = uint2{lo, hi};
      } else {
#pragma unroll
        for (int r = 0; r < 4; ++r)
          vbuf[((size_t)b * CDIM + (ro - 2 * CDIM + r)) * NSEQ + p] =
              f2bf(acc[m][n][r]);
      }
    }
  }
}

// ------------- kernel: flash attention ----------------------------------
// K/V slabs [64 rows][64 cols] (128 B pitch) with 8-chunk XOR swizzle via
// pre-swizzled global source; ds_read_b128 lands 2-way (free).
__global__ __launch_bounds__(256) void k_attn(const u16* __restrict__ qkT,
                                              const u16* __restrict__ vbuf,
                                              u16* __restrict__ attnT) {
  int id = blockIdx.x;
  int b = id & 7;
  int j = id >> 3;
  int h = j % 12;
  int nt0 = (j / 12) * 128;

  int t = threadIdx.x, lane = t & 63, wid = t >> 6;
  int ln = lane & 15, quad = lane >> 4;
  int nbase = nt0 + wid * 32;

  __shared__ u16 Ks[2][64 * 64];
  __shared__ u16 Vs[2][64 * 64];
  __shared__ u16 Pa[4][32 * 72];
  u16* myP = Pa[wid];

  const u16* qbase = qkT + ((size_t)b * NSEQ + nbase) * 1536 + h * DH;
  bf16x8 aq[2][2];
#pragma unroll
  for (int mt = 0; mt < 2; ++mt)
#pragma unroll
    for (int ks = 0; ks < 2; ++ks)
      aq[mt][ks] = *(const bf16x8*)&qbase[(size_t)(mt * 16 + ln) * 1536 + ks * 32 + quad * 8];

  bf16x8 ones;
#pragma unroll
  for (int i = 0; i < 8; ++i) ones[i] = __builtin_bit_cast(__bf16, (u16)0x3F80);

  v4f oacc[2][4] = {};
  v4f lacc[2] = {};

  int sr8 = lane >> 3;
  int sch = ((lane & 7) ^ sr8) * 8;
  const u16* kg0 = qkT + ((size_t)b * NSEQ + wid * 16 + sr8) * 1536 + CDIM + h * DH + sch;
  const u16* vg0 = vbuf + ((size_t)b * CDIM + h * DH + wid * 16 + sr8) * NSEQ + sch;
  int sK = (wid * 16) * 64;

  int sw0 = (quad ^ (ln & 7)) * 8;
  int sw1 = ((4 + quad) ^ (ln & 7)) * 8;

  gload16(kg0, &Ks[0][sK]);
  gload16(kg0 + (size_t)8 * 1536, &Ks[0][sK + 512]);
  gload16(vg0, &Vs[0][sK]);
  gload16(vg0 + 8 * NSEQ, &Vs[0][sK + 512]);
  __syncthreads();

  for (int s = 0; s < 16; ++s) {
    int cur = s & 1, nxt = cur ^ 1;
    if (s < 15) {
      size_t ko = (size_t)(s + 1) * 64 * 1536;
      int vo = (s + 1) * 64;
      gload16(kg0 + ko, &Ks[nxt][sK]);
      gload16(kg0 + ko + (size_t)8 * 1536, &Ks[nxt][sK + 512]);
      gload16(vg0 + vo, &Vs[nxt][sK]);
      gload16(vg0 + vo + 8 * NSEQ, &Vs[nxt][sK + 512]);
    }

#pragma unroll
    for (int ct = 0; ct < 4; ++ct) {
      bf16x8 kf0 = *(const bf16x8*)&Ks[cur][(ct * 16 + ln) * 64 + sw0];
      bf16x8 kf1 = *(const bf16x8*)&Ks[cur][(ct * 16 + ln) * 64 + sw1];
#pragma unroll
      for (int mt = 0; mt < 2; ++mt) {
        v4f sc = {};
        sc = mfma16(kf0, aq[mt][0], sc);
        sc = mfma16(kf1, aq[mt][1], sc);
        float p0 = __builtin_amdgcn_exp2f(sc[0] * SCL);
        float p1 = __builtin_amdgcn_exp2f(sc[1] * SCL);
        float p2 = __builtin_amdgcn_exp2f(sc[2] * SCL);
        float p3 = __builtin_amdgcn_exp2f(sc[3] * SCL);
        *(uint2*)&myP[(mt * 16 + ln) * 72 + ct * 16 + quad * 4] =
            uint2{pkbf(p1, p0), pkbf(p3, p2)};
      }
    }

    bf16x8 ap[2][2];
#pragma unroll
    for (int mt = 0; mt < 2; ++mt)
#pragma unroll
      for (int ks = 0; ks < 2; ++ks)
        ap[mt][ks] = *(const bf16x8*)&myP[(mt * 16 + ln) * 72 + ks * 32 + quad * 8];
#pragma unroll
    for (int mt = 0; mt < 2; ++mt) {
      lacc[mt] = mfma16(ap[mt][0], ones, lacc[mt]);
      lacc[mt] = mfma16(ap[mt][1], ones, lacc[mt]);
    }
#pragma unroll
    for (int nt = 0; nt < 4; ++nt) {
      bf16x8 vf0 = *(const bf16x8*)&Vs[cur][(nt * 16 + ln) * 64 + sw0];
      bf16x8 vf1 = *(const bf16x8*)&Vs[cur][(nt * 16 + ln) * 64 + sw1];
#pragma unroll
      for (int mt = 0; mt < 2; ++mt) {
        oacc[mt][nt] = mfma16(ap[mt][0], vf0, oacc[mt][nt]);
        oacc[mt][nt] = mfma16(ap[mt][1], vf1, oacc[mt][nt]);
      }
    }
    __syncthreads();
  }

#pragma unroll
  for (int mt = 0; mt < 2; ++mt) {
#pragma unroll
    for (int r = 0; r < 4; ++r) {
      float inv = 1.0f / lacc[mt][r];
      int n = nbase + mt * 16 + quad * 4 + r;
      u16* dst = attnT + ((size_t)b * NSEQ + n) * CDIM + h * DH;
#pragma unroll
      for (int nt = 0; nt < 4; ++nt)
        dst[nt * 16 + ln] = b16(oacc[mt][nt][r] * inv);
    }
  }
}

// ------------- kernel: proj GEMM ----------------------------------------
__global__ __launch_bounds__(256, 3) void k_gemm_proj(const u16* __restrict__ Wb,
                                                      const u16* __restrict__ aT,
                                                      float* __restrict__ out) {
  __shared__ u16 sm[2 * 12288];   // 48 KB
  int bid = blockIdx.x;
  int swz = (bid & 7) * 24 + (bid >> 3);   // bijective: 192 % 8 == 0
  int oIdx = swz % 3, pIdx = swz / 3;
  int oT = oIdx * 256;
  int pG = pIdx * 128;

  v4f acc[8][4] = {};
  gemm_core(Wb + (size_t)oT * CDIM, aT + (size_t)pG * CDIM, sm, acc);

  int t = threadIdx.x, lane = t & 63, wid = t >> 6;
  int ln = lane & 15, quad = lane >> 4;
  int wm = wid >> 1, wn = wid & 1;
#pragma unroll
  for (int m = 0; m < 8; ++m) {
#pragma unroll
    for (int n = 0; n < 4; ++n) {
      int ro = oT + wm * 128 + m * 16 + quad * 4;
      int cp = pG + wn * 64 + n * 16 + ln;
      int b = cp >> 10, p = cp & 1023;
#pragma unroll
      for (int r = 0; r < 4; ++r)
        out[((size_t)b * CDIM + ro + r) * NSEQ + p] = acc[m][n][r];
    }
  }
}

extern "C" void kernel_launch(void* const* d_in, const int* in_sizes, int n_in,
                              void* d_out, int out_size, void* d_ws, size_t ws_size,
                              hipStream_t stream) {
  const float* x = (const float*)d_in[0];
  const float* w_qkv = (const float*)d_in[1];
  const float* w_proj = (const float*)d_in[2];
  float* out = (float*)d_out;

  char* ws = (char*)d_ws;
  u16* wqkv_bf = (u16*)(ws);
  u16* wproj_bf = (u16*)(ws + 3538944);
  u16* xT = (u16*)(ws + 4718592);
  u16* vbuf = (u16*)(ws + 17301504);
  u16* qkT = (u16*)d_out;
  u16* attnT = xT;

  k_prep<<<dim3(3840), dim3(256), 0, stream>>>(x, w_qkv, w_proj, xT, wqkv_bf, wproj_bf);
  k_gemm_qkv<<<dim3(576), dim3(256), 0, stream>>>(wqkv_bf, xT, qkT, vbuf);
  k_attn<<<dim3(768), dim3(256), 0, stream>>>(qkT, vbuf, attnT);
  k_gemm_proj<<<dim3(192), dim3(256), 0, stream>>>(wproj_bf, attnT, out);
}

// Round 8
// 176.634 us; speedup vs baseline: 1.2381x; 1.2381x over previous
//
#include <hip/hip_runtime.h>

typedef unsigned short u16;
typedef unsigned int u32;
typedef float v4f __attribute__((ext_vector_type(4)));
typedef __bf16 bf16x8 __attribute__((ext_vector_type(8)));

#define BATCH 8
#define CDIM 768
#define NHEAD 12
#define DH 64
#define NSEQ 1024
#define SCL 0.18033688011112042f

__device__ __forceinline__ u16 f2bf(float f) {
  u32 u = __builtin_bit_cast(u32, f);
  u += 0x7fffu + ((u >> 16) & 1u);   // RNE
  return (u16)(u >> 16);
}

__device__ __forceinline__ u16 b16(float f) {
  return (u16)((__builtin_bit_cast(u32, f) + 0x8000u) >> 16);
}

__device__ __forceinline__ u32 pkbf(float hi, float lo) {
  u32 a = __builtin_bit_cast(u32, hi) + 0x8000u;
  u32 b = __builtin_bit_cast(u32, lo) + 0x8000u;
  return __builtin_amdgcn_perm(a, b, 0x07060302u);  // {a[31:16], b[31:16]}
}

__device__ __forceinline__ v4f mfma16(bf16x8 a, bf16x8 b, v4f c) {
  return __builtin_amdgcn_mfma_f32_16x16x32_bf16(a, b, c, 0, 0, 0);
}

__device__ __forceinline__ void gload16(const u16* g, u16* l) {
  __builtin_amdgcn_global_load_lds(
      (const __attribute__((address_space(1))) void*)g,
      (__attribute__((address_space(3))) void*)l, 16, 0, 0);
}

#define BARQ asm volatile("s_barrier" ::: "memory")
#define LGKM0 asm volatile("s_waitcnt lgkmcnt(0)" ::: "memory")
#define VMC0 asm volatile("s_waitcnt vmcnt(0)" ::: "memory")
#define FEN asm volatile("" ::: "memory")

// ------------- kernel: fused prep --------------------------------------
__global__ __launch_bounds__(256) void k_prep(const float* __restrict__ x,
                                              const float* __restrict__ wq,
                                              const float* __restrict__ wp,
                                              u16* __restrict__ xT,
                                              u16* __restrict__ wqb,
                                              u16* __restrict__ wpb) {
  __shared__ u16 Ts[64][72];
  int bid = blockIdx.x;
  int t = threadIdx.x;
  if (bid < 2304) {
    bool isQ = bid < 1728;
    const float* s = isQ ? wq : wp;
    u16* d = isQ ? wqb : wpb;
    int i = (isQ ? bid : bid - 1728) * 256 + t;
    float4 v = ((const float4*)s)[i];
    u32 lo = (u32)f2bf(v.x) | ((u32)f2bf(v.y) << 16);
    u32 hi = (u32)f2bf(v.z) | ((u32)f2bf(v.w) << 16);
    ((uint2*)d)[i] = uint2{lo, hi};
    return;
  }
  int id = bid - 2304;
  int p0 = (id & 15) * 64; id >>= 4;
  int c0 = (id % 12) * 64; int b = id / 12;
  int cr = t >> 4;
  int p4 = (t & 15) * 4;
  const float* src = x + ((size_t)b * CDIM + c0) * NSEQ + p0;
#pragma unroll
  for (int i = 0; i < 4; ++i) {
    int c = cr + i * 16;
    float4 v = *(const float4*)&src[(size_t)c * NSEQ + p4];
    Ts[p4 + 0][c] = f2bf(v.x);
    Ts[p4 + 1][c] = f2bf(v.y);
    Ts[p4 + 2][c] = f2bf(v.z);
    Ts[p4 + 3][c] = f2bf(v.w);
  }
  __syncthreads();
  int p = t >> 2;
  int cq = t & 3;
  u16* dst = xT + ((size_t)b * NSEQ + p0 + p) * CDIM + c0;
#pragma unroll
  for (int j = 0; j < 2; ++j) {
    int ch = cq + j * 4;
    *(int4*)&dst[ch * 8] = *(const int4*)&Ts[p][ch * 8];
  }
}

#define NKT 24     // CDIM/32

// ------------- kernel: QKV GEMM, 288x256 tile, 256 blocks (balanced) ----
// 512 thr / 8 waves (2M x 4N), wave-tile 144x64 (acc[9][4]), BK=32,
// 2 phases/tile (20+16 MFMA). 3-buf LDS 102 KB -> 1 block/CU, grid = 256
// = exactly one balanced round (the R5 2-round tail was the killer).
// Staging role-split: waves 0-5 stage A (3 gload16/tile each),
// waves 6-7 stage B (8 each). Tile j+2 issued at TOP of phase A(j)
// (~3.5-phase window > HBM latency); counted drain vmcnt(3)/vmcnt(8)
// (wave-role-uniform) at mid-phase-B — never 0 mid-loop.
// Chunk-XOR swizzle as R4 (slot = chunk ^ ((row>>1)&3), 64B rows): 2-way
// bank aliasing = free; staged via pre-swizzled global source.
__global__ __launch_bounds__(512, 2) void k_gemm_qkv(const u16* __restrict__ Wb,
                                                     const u16* __restrict__ xT,
                                                     u16* __restrict__ qkT,
                                                     u16* __restrict__ vbuf) {
  __shared__ u16 sm[3 * 17408];   // 3 bufs x (A 288x32 + B 256x32) = 102 KB
  int bid = blockIdx.x;
  int swz = (bid & 7) * 32 + (bid >> 3);   // bijective: 256 % 8 == 0
  int oIdx = swz % 8, pIdx = swz / 8;      // per XCD: pIdx in [4x,4x+4) = batch x
  int oT = oIdx * 288;
  int pG = pIdx * 256;

  int t = threadIdx.x, lane = t & 63, wid = t >> 6;
  int ln = lane & 15, quad = lane >> 4;
  int wm = wid >> 2, wn = wid & 3;

  // staging addressing: per gload16, 16 rows x 4 chunks; stored chunk slot
  // (l&3) sources global chunk (l&3)^((l>>3)&3)  [== (l&3)^((row>>1)&3)].
  int lrow = lane >> 2;
  int scg = ((lane & 3) ^ ((lane >> 3) & 3)) * 8;
  bool roleA = wid < 6;
  int w6 = wid - 6;
  const u16* Asrc = Wb + (size_t)(oT + wid * 48 + lrow) * CDIM + scg;       // roleA
  const u16* Bsrc = xT + (size_t)(pG + (w6 < 0 ? 0 : w6) * 128 + lrow) * CDIM + scg;
  int ldA = wid * 1536;            // u16: rows wid*48 .. +48 within A region
  int ldB = 9216 + (w6 < 0 ? 0 : w6) * 4096;   // B region at 9216

#define STAGEQ(bi, kt) do {                                                \
    u16* bb_ = sm + (bi) * 17408;                                          \
    if (roleA) {                                                           \
      const u16* gp_ = Asrc + (kt) * 32;                                   \
      gload16(gp_, bb_ + ldA);                                             \
      gload16(gp_ + (size_t)16 * CDIM, bb_ + ldA + 512);                   \
      gload16(gp_ + (size_t)32 * CDIM, bb_ + ldA + 1024);                  \
    } else {                                                               \
      const u16* gp_ = Bsrc + (kt) * 32;                                   \
      _Pragma("unroll") for (int i_ = 0; i_ < 8; ++i_)                     \
        gload16(gp_ + (size_t)i_ * 16 * CDIM, bb_ + ldB + i_ * 512);       \
    }                                                                      \
  } while (0)

#define DRAINQ do {                                                        \
    if (roleA) asm volatile("s_waitcnt vmcnt(3)" ::: "memory");            \
    else asm volatile("s_waitcnt vmcnt(8)" ::: "memory");                  \
  } while (0)

  // fragment reads: data chunk quad of row r lives at slot quad^((r>>1)&3)
  int slot = (quad ^ ((ln >> 1) & 3)) * 8;
  int rAr = (wm * 144 + ln) * 32;
  int rBr = 9216 + (wn * 64 + ln) * 32;

  v4f acc[9][4] = {};

  // ---- prologue: tiles 0,1 into bufs 0,1 (order-fenced for vmcnt) ----
  STAGEQ(0, 0);
  FEN;
  STAGEQ(1, 1);
  DRAINQ;            // tile 0 resident, tile 1 in flight
  BARQ;

  for (int j = 0; j < NKT; ++j) {
    const u16* sb = sm + (j % 3) * 17408;
    int bi2 = (j + 2) % 3;

    // ---- phase A: issue tile j+2; read A m0-4 + B; 20 MFMA ----
    if (j < NKT - 2) STAGEQ(bi2, j + 2);
    bf16x8 af[5], bfr[4];
#pragma unroll
    for (int m = 0; m < 5; ++m)
      af[m] = *(const bf16x8*)&sb[rAr + m * 512 + slot];
#pragma unroll
    for (int n = 0; n < 4; ++n)
      bfr[n] = *(const bf16x8*)&sb[rBr + n * 512 + slot];
    BARQ;
    LGKM0;
    __builtin_amdgcn_sched_barrier(0);
    __builtin_amdgcn_s_setprio(1);
#pragma unroll
    for (int m = 0; m < 5; ++m)
#pragma unroll
      for (int n = 0; n < 4; ++n)
        acc[m][n] = mfma16(af[m], bfr[n], acc[m][n]);
    __builtin_amdgcn_s_setprio(0);
    BARQ;

    // ---- phase B: read A m5-8; counted drain of tile j+1; 16 MFMA ----
    bf16x8 ag[4];
#pragma unroll
    for (int m = 0; m < 4; ++m)
      ag[m] = *(const bf16x8*)&sb[rAr + (m + 5) * 512 + slot];
    if (j < NKT - 2) DRAINQ;
    else if (j == NKT - 2) VMC0;
    BARQ;
    LGKM0;
    __builtin_amdgcn_sched_barrier(0);
    __builtin_amdgcn_s_setprio(1);
#pragma unroll
    for (int m = 0; m < 4; ++m)
#pragma unroll
      for (int n = 0; n < 4; ++n)
        acc[m + 5][n] = mfma16(ag[m], bfr[n], acc[m + 5][n]);
    __builtin_amdgcn_s_setprio(0);
    BARQ;
  }

  // ---- epilogue: ro < 1536 -> qkT (transposed), else -> vbuf ----
  // V-boundary 1536 falls on a fragment boundary (1536-1440 = 96 = 6*16).
#pragma unroll
  for (int m = 0; m < 9; ++m) {
#pragma unroll
    for (int n = 0; n < 4; ++n) {
      int ro = oT + wm * 144 + m * 16 + quad * 4;
      int cp = pG + wn * 64 + n * 16 + ln;
      int b = cp >> 10, p = cp & 1023;
      if (ro < 2 * CDIM) {
        u32 lo = (u32)f2bf(acc[m][n][0]) | ((u32)f2bf(acc[m][n][1]) << 16);
        u32 hi = (u32)f2bf(acc[m][n][2]) | ((u32)f2bf(acc[m][n][3]) << 16);
        *(uint2*)&qkT[((size_t)b * NSEQ + p) * 1536 + ro] = uint2{lo, hi};
      } else {
#pragma unroll
        for (int r = 0; r < 4; ++r)
          vbuf[((size_t)b * CDIM + (ro - 2 * CDIM + r)) * NSEQ + p] =
              f2bf(acc[m][n][r]);
      }
    }
  }
#undef STAGEQ
#undef DRAINQ
}

// ------------- 256x128 3-buf pipelined GEMM core (R4, for proj) ---------
__device__ __forceinline__ void gemm_core(const u16* __restrict__ Ag,
                                          const u16* __restrict__ Bg,
                                          u16* sm, v4f (&acc)[8][4]) {
  int t = threadIdx.x, lane = t & 63, wid = t >> 6;
  int ln = lane & 15, quad = lane >> 4;
  int wm = wid >> 1, wn = wid & 1;

  int srow = wid * 16 + (lane >> 2);
  int scg = ((lane & 3) ^ ((lane >> 3) & 3)) * 8;
  const u16* As0 = Ag + (size_t)srow * CDIM + scg;
  const u16* Bs0 = Bg + (size_t)srow * CDIM + scg;
  int ldw = wid * 512;

  int cA = (quad ^ ((ln >> 1) & 3)) * 8;
  int rA = (wm * 128 + ln) * 32;
  int rB = 8192 + (wn * 64 + ln) * 32;

  {
    u16* sb0 = sm;
    gload16(As0, sb0 + ldw);
    gload16(As0 + (size_t)64 * CDIM, sb0 + 2048 + ldw);
    gload16(As0 + (size_t)128 * CDIM, sb0 + 4096 + ldw);
    gload16(As0 + (size_t)192 * CDIM, sb0 + 6144 + ldw);
    gload16(Bs0, sb0 + 8192 + ldw);
    gload16(Bs0 + (size_t)64 * CDIM, sb0 + 10240 + ldw);
  }
  FEN;
  {
    u16* sb1 = sm + 12288;
    gload16(As0 + 32, sb1 + ldw);
    gload16(As0 + (size_t)64 * CDIM + 32, sb1 + 2048 + ldw);
    gload16(As0 + (size_t)128 * CDIM + 32, sb1 + 4096 + ldw);
    gload16(As0 + (size_t)192 * CDIM + 32, sb1 + 6144 + ldw);
    gload16(Bs0 + 32, sb1 + 8192 + ldw);
    gload16(Bs0 + (size_t)64 * CDIM + 32, sb1 + 10240 + ldw);
  }
  asm volatile("s_waitcnt vmcnt(6)" ::: "memory");
  BARQ;

  for (int kb = 0; kb < 8; ++kb) {
#pragma unroll
    for (int u = 0; u < 3; ++u) {
      int kt = kb * 3 + u;
      const u16* sb = sm + u * 12288;
      u16* nb = sm + ((u + 2) % 3) * 12288;
      int ko = (kt + 2) * 32;

      bf16x8 af[4], bfr[4];
#pragma unroll
      for (int m = 0; m < 4; ++m)
        af[m] = *(const bf16x8*)&sb[rA + m * 512 + cA];
#pragma unroll
      for (int n = 0; n < 4; ++n)
        bfr[n] = *(const bf16x8*)&sb[rB + n * 512 + cA];
      if (kt < NKT - 2) {
        gload16(As0 + ko, nb + ldw);
        gload16(As0 + (size_t)64 * CDIM + ko, nb + 2048 + ldw);
        gload16(Bs0 + ko, nb + 8192 + ldw);
      }
      BARQ;
      LGKM0;
      __builtin_amdgcn_sched_barrier(0);
      __builtin_amdgcn_s_setprio(1);
#pragma unroll
      for (int m = 0; m < 4; ++m)
#pragma unroll
        for (int n = 0; n < 4; ++n)
          acc[m][n] = mfma16(af[m], bfr[n], acc[m][n]);
      __builtin_amdgcn_s_setprio(0);
      BARQ;

#pragma unroll
      for (int m = 0; m < 4; ++m)
        af[m] = *(const bf16x8*)&sb[rA + (m + 4) * 512 + cA];
      if (kt < NKT - 2) {
        gload16(As0 + (size_t)128 * CDIM + ko, nb + 4096 + ldw);
        gload16(As0 + (size_t)192 * CDIM + ko, nb + 6144 + ldw);
        gload16(Bs0 + (size_t)64 * CDIM + ko, nb + 10240 + ldw);
        asm volatile("s_waitcnt vmcnt(6)" ::: "memory");
      } else if (kt == NKT - 2) {
        VMC0;
      }
      BARQ;
      LGKM0;
      __builtin_amdgcn_sched_barrier(0);
      __builtin_amdgcn_s_setprio(1);
#pragma unroll
      for (int m = 0; m < 4; ++m)
#pragma unroll
        for (int n = 0; n < 4; ++n)
          acc[m + 4][n] = mfma16(af[m], bfr[n], acc[m + 4][n]);
      __builtin_amdgcn_s_setprio(0);
      BARQ;
    }
  }
}

// ------------- kernel: flash attention (R4, unchanged) ------------------
__global__ __launch_bounds__(256) void k_attn(const u16* __restrict__ qkT,
                                              const u16* __restrict__ vbuf,
                                              u16* __restrict__ attnT) {
  int id = blockIdx.x;
  int b = id & 7;
  int j = id >> 3;
  int h = j % 12;
  int nt0 = (j / 12) * 128;

  int t = threadIdx.x, lane = t & 63, wid = t >> 6;
  int ln = lane & 15, quad = lane >> 4;
  int nbase = nt0 + wid * 32;

  __shared__ u16 Ks[2][64 * 64];
  __shared__ u16 Vs[2][64 * 64];
  __shared__ u16 Pa[4][32 * 72];
  u16* myP = Pa[wid];

  const u16* qbase = qkT + ((size_t)b * NSEQ + nbase) * 1536 + h * DH;
  bf16x8 aq[2][2];
#pragma unroll
  for (int mt = 0; mt < 2; ++mt)
#pragma unroll
    for (int ks = 0; ks < 2; ++ks)
      aq[mt][ks] = *(const bf16x8*)&qbase[(size_t)(mt * 16 + ln) * 1536 + ks * 32 + quad * 8];

  bf16x8 ones;
#pragma unroll
  for (int i = 0; i < 8; ++i) ones[i] = __builtin_bit_cast(__bf16, (u16)0x3F80);

  v4f oacc[2][4] = {};
  v4f lacc[2] = {};

  int sr8 = lane >> 3;
  int sch = ((lane & 7) ^ sr8) * 8;
  const u16* kg0 = qkT + ((size_t)b * NSEQ + wid * 16 + sr8) * 1536 + CDIM + h * DH + sch;
  const u16* vg0 = vbuf + ((size_t)b * CDIM + h * DH + wid * 16 + sr8) * NSEQ + sch;
  int sK = (wid * 16) * 64;

  int sw0 = (quad ^ (ln & 7)) * 8;
  int sw1 = ((4 + quad) ^ (ln & 7)) * 8;

  gload16(kg0, &Ks[0][sK]);
  gload16(kg0 + (size_t)8 * 1536, &Ks[0][sK + 512]);
  gload16(vg0, &Vs[0][sK]);
  gload16(vg0 + 8 * NSEQ, &Vs[0][sK + 512]);
  __syncthreads();

  for (int s = 0; s < 16; ++s) {
    int cur = s & 1, nxt = cur ^ 1;
    if (s < 15) {
      size_t ko = (size_t)(s + 1) * 64 * 1536;
      int vo = (s + 1) * 64;
      gload16(kg0 + ko, &Ks[nxt][sK]);
      gload16(kg0 + ko + (size_t)8 * 1536, &Ks[nxt][sK + 512]);
      gload16(vg0 + vo, &Vs[nxt][sK]);
      gload16(vg0 + vo + 8 * NSEQ, &Vs[nxt][sK + 512]);
    }

#pragma unroll
    for (int ct = 0; ct < 4; ++ct) {
      bf16x8 kf0 = *(const bf16x8*)&Ks[cur][(ct * 16 + ln) * 64 + sw0];
      bf16x8 kf1 = *(const bf16x8*)&Ks[cur][(ct * 16 + ln) * 64 + sw1];
#pragma unroll
      for (int mt = 0; mt < 2; ++mt) {
        v4f sc = {};
        sc = mfma16(kf0, aq[mt][0], sc);
        sc = mfma16(kf1, aq[mt][1], sc);
        float p0 = __builtin_amdgcn_exp2f(sc[0] * SCL);
        float p1 = __builtin_amdgcn_exp2f(sc[1] * SCL);
        float p2 = __builtin_amdgcn_exp2f(sc[2] * SCL);
        float p3 = __builtin_amdgcn_exp2f(sc[3] * SCL);
        *(uint2*)&myP[(mt * 16 + ln) * 72 + ct * 16 + quad * 4] =
            uint2{pkbf(p1, p0), pkbf(p3, p2)};
      }
    }

    bf16x8 ap[2][2];
#pragma unroll
    for (int mt = 0; mt < 2; ++mt)
#pragma unroll
      for (int ks = 0; ks < 2; ++ks)
        ap[mt][ks] = *(const bf16x8*)&myP[(mt * 16 + ln) * 72 + ks * 32 + quad * 8];
#pragma unroll
    for (int mt = 0; mt < 2; ++mt) {
      lacc[mt] = mfma16(ap[mt][0], ones, lacc[mt]);
      lacc[mt] = mfma16(ap[mt][1], ones, lacc[mt]);
    }
#pragma unroll
    for (int nt = 0; nt < 4; ++nt) {
      bf16x8 vf0 = *(const bf16x8*)&Vs[cur][(nt * 16 + ln) * 64 + sw0];
      bf16x8 vf1 = *(const bf16x8*)&Vs[cur][(nt * 16 + ln) * 64 + sw1];
#pragma unroll
      for (int mt = 0; mt < 2; ++mt) {
        oacc[mt][nt] = mfma16(ap[mt][0], vf0, oacc[mt][nt]);
        oacc[mt][nt] = mfma16(ap[mt][1], vf1, oacc[mt][nt]);
      }
    }
    __syncthreads();
  }

#pragma unroll
  for (int mt = 0; mt < 2; ++mt) {
#pragma unroll
    for (int r = 0; r < 4; ++r) {
      float inv = 1.0f / lacc[mt][r];
      int n = nbase + mt * 16 + quad * 4 + r;
      u16* dst = attnT + ((size_t)b * NSEQ + n) * CDIM + h * DH;
#pragma unroll
      for (int nt = 0; nt < 4; ++nt)
        dst[nt * 16 + ln] = b16(oacc[mt][nt][r] * inv);
    }
  }
}

// ------------- kernel: proj GEMM (R4, unchanged) ------------------------
__global__ __launch_bounds__(256, 2) void k_gemm_proj(const u16* __restrict__ Wb,
                                                      const u16* __restrict__ aT,
                                                      float* __restrict__ out) {
  __shared__ u16 sm[3 * 12288];   // 72 KB
  int bid = blockIdx.x;
  int swz = (bid & 7) * 24 + (bid >> 3);   // bijective: 192 % 8 == 0
  int oIdx = swz % 3, pIdx = swz / 3;
  int oT = oIdx * 256;
  int pG = pIdx * 128;

  v4f acc[8][4] = {};
  gemm_core(Wb + (size_t)oT * CDIM, aT + (size_t)pG * CDIM, sm, acc);

  int t = threadIdx.x, lane = t & 63, wid = t >> 6;
  int ln = lane & 15, quad = lane >> 4;
  int wm = wid >> 1, wn = wid & 1;
#pragma unroll
  for (int m = 0; m < 8; ++m) {
#pragma unroll
    for (int n = 0; n < 4; ++n) {
      int ro = oT + wm * 128 + m * 16 + quad * 4;
      int cp = pG + wn * 64 + n * 16 + ln;
      int b = cp >> 10, p = cp & 1023;
#pragma unroll
      for (int r = 0; r < 4; ++r)
        out[((size_t)b * CDIM + ro + r) * NSEQ + p] = acc[m][n][r];
    }
  }
}

extern "C" void kernel_launch(void* const* d_in, const int* in_sizes, int n_in,
                              void* d_out, int out_size, void* d_ws, size_t ws_size,
                              hipStream_t stream) {
  const float* x = (const float*)d_in[0];
  const float* w_qkv = (const float*)d_in[1];
  const float* w_proj = (const float*)d_in[2];
  float* out = (float*)d_out;

  char* ws = (char*)d_ws;
  u16* wqkv_bf = (u16*)(ws);
  u16* wproj_bf = (u16*)(ws + 3538944);
  u16* xT = (u16*)(ws + 4718592);
  u16* vbuf = (u16*)(ws + 17301504);
  u16* qkT = (u16*)d_out;
  u16* attnT = xT;

  k_prep<<<dim3(3840), dim3(256), 0, stream>>>(x, w_qkv, w_proj, xT, wqkv_bf, wproj_bf);
  k_gemm_qkv<<<dim3(256), dim3(512), 0, stream>>>(wqkv_bf, xT, qkT, vbuf);
  k_attn<<<dim3(768), dim3(256), 0, stream>>>(qkT, vbuf, attnT);
  k_gemm_proj<<<dim3(192), dim3(256), 0, stream>>>(wproj_bf, attnT, out);
}